// Round 5
// baseline (461.635 us; speedup 1.0000x reference)
//
#include <hip/hip_runtime.h>
#include <hip/hip_bf16.h>

typedef __bf16 bf16x8 __attribute__((ext_vector_type(8)));
typedef __bf16 bf16x4v __attribute__((ext_vector_type(4)));
typedef float f32x4 __attribute__((ext_vector_type(4)));
typedef float f32x16 __attribute__((ext_vector_type(16)));
typedef unsigned int u32;
typedef u32 u32x4 __attribute__((ext_vector_type(4)));
typedef unsigned short u16;

#define MFMA16(a, b, c) __builtin_amdgcn_mfma_f32_16x16x32_bf16((a), (b), (c), 0, 0, 0)
#define MFMA32(a, b, c) __builtin_amdgcn_mfma_f32_32x32x16_bf16((a), (b), (c), 0, 0, 0)

static constexpr float QSCALE = 0.09016844f;   // 256^-0.5 * log2(e) (folded into qh)
static constexpr float MADD   = -14427.0f;     // -10000 * log2(e)   (rank-1 mask add)

__device__ inline u32 pk2(float a, float b) {
    u16 x = __builtin_bit_cast(u16, (__bf16)a);
    u16 y = __builtin_bit_cast(u16, (__bf16)b);
    return (u32)x | ((u32)y << 16);
}

// async global->LDS, 16B per lane, linear dest (base + lane*16)
__device__ inline void gl16(const void* g, void* l) {
    __builtin_amdgcn_global_load_lds((const __attribute__((address_space(1))) u32*)g,
                                     (__attribute__((address_space(3))) u32*)l, 16, 0, 0);
}

// ------------- weight pre-convert: f32 [256][256] -> bf16, XOR-pre-swizzled -------------
// wbf[n][g] = W[n][ (g&~7) | ((g&7)^(n&7)) ]   (g = 16B chunk index, 0..31)
__global__ __launch_bounds__(256, 8)
void wcvt_kernel(const float* __restrict__ Wq, const float* __restrict__ Wk,
                 const float* __restrict__ Wv, const float* __restrict__ Wp,
                 __bf16* __restrict__ wbf)
{
    const int bid = blockIdx.x;            // 128 blocks: widx = bid>>5
    const int widx = bid >> 5;
    const float* W = widx == 0 ? Wq : widx == 1 ? Wk : widx == 2 ? Wv : Wp;
    const int tid = (bid & 31) * 256 + threadIdx.x;   // 0..8191
    const int n = tid >> 5, g = tid & 31;
    const int sg = (g & ~7) | ((g & 7) ^ (n & 7));
    const float* src = W + n * 256 + sg * 8;
    float4 a = *(const float4*)src;
    float4 b = *(const float4*)(src + 4);
    bf16x8 o8 = { (__bf16)a.x, (__bf16)a.y, (__bf16)a.z, (__bf16)a.w,
                  (__bf16)b.x, (__bf16)b.y, (__bf16)b.z, (__bf16)b.w };
    *(bf16x8*)&wbf[(size_t)widx * 65536 + n * 256 + g * 8] = o8;
}

// ---------------- projection GEMM: Y = X @ W^T, 64M x 256N block ----------------
// X: [M,256] (f32 or bf16); wbf: pre-swizzled bf16 W (row n = weights of out col n)
// Y bf16 (scaled) or f32; TRANS_OUT: per-4096-row batch, write Y^T [b][n][m%4096] bf16.
template<bool IN_F32, bool OUT_F32, bool TRANS_OUT>
__global__ __launch_bounds__(256, 2)
void proj_kernel(const void* __restrict__ Xv, const __bf16* __restrict__ wbf,
                 void* __restrict__ Yv, float oscale)
{
    __shared__ __bf16 lds_a[64][72];       // X tile, padded
    __shared__ __bf16 lds_w[256][64];      // W k-slice [256 n][64 k], XOR-swizzled chunks
    const int t = threadIdx.x;
    const int row0 = blockIdx.x * 64;
    const int lane = t & 63, w = t >> 6;
    const int wr = w >> 1, wc = w & 1;     // 2x2 waves: 32-row x 128-col
    const int lr = lane & 15, lg = lane >> 4;

    f32x4 acc[2][8] = {};

    for (int kk = 0; kk < 4; ++kk) {
        __syncthreads();
        // W stage: pure async copy (swizzle pre-baked in wbf); 8 rows per gl16
        {
            char* lw = (char*)&lds_w[0][0];
            const char* src = (const char*)(wbf + kk * 64);   // row n stride 512B
            #pragma unroll
            for (int i = 0; i < 2; ++i) {
                int r = i * 32 + w * 8 + (lane >> 3);          // wait: 4 waves * 8 rows * 2 = 64? need 256 rows
                (void)r;
            }
            // 256 rows, 8 chunks each: 2048 chunk-slots / 256 thr = 8 gl16 each
            #pragma unroll
            for (int i = 0; i < 8; ++i) {
                int r = i * 32 + w * 8 + (lane >> 3);          // 0..255
                gl16(src + (size_t)r * 512 + (lane & 7) * 16,
                     lw + i * 4096 + w * 1024 + (lane & 63) * 16);
            }
        }
        if constexpr (IN_F32) {
            const float* X = (const float*)Xv;
            #pragma unroll
            for (int p = 0; p < 4; ++p) {
                int idx4 = p * 256 + t;                        // 1024 float4 (64x64)
                int r = idx4 >> 4, c4 = (idx4 & 15) << 2;
                float4 v4 = *(const float4*)&X[(size_t)(row0 + r) * 256 + kk * 64 + c4];
                bf16x4v pk = { (__bf16)v4.x, (__bf16)v4.y, (__bf16)v4.z, (__bf16)v4.w };
                *(bf16x4v*)&lds_a[r][c4] = pk;
            }
        } else {
            const __bf16* X = (const __bf16*)Xv;
            #pragma unroll
            for (int p = 0; p < 2; ++p) {
                int idx8 = p * 256 + t;                        // 512 chunks of 8 bf16
                int r = idx8 >> 3, c8 = (idx8 & 7) << 3;
                *(bf16x8*)&lds_a[r][c8] = *(const bf16x8*)&X[(size_t)(row0 + r) * 256 + kk * 64 + c8];
            }
        }
        __syncthreads();
        #pragma unroll
        for (int ks = 0; ks < 2; ++ks) {
            bf16x8 af[2], bfr[8];
            #pragma unroll
            for (int i = 0; i < 2; ++i)
                af[i] = *(bf16x8*)&lds_a[wr * 32 + i * 16 + lr][ks * 32 + 8 * lg];
            #pragma unroll
            for (int j = 0; j < 8; ++j) {
                int rw = wc * 128 + j * 16 + lr;
                int ch = (ks * 4 + lg) ^ (rw & 7);
                bfr[j] = *(bf16x8*)((char*)&lds_w[0][0] + rw * 128 + ch * 16);
            }
            #pragma unroll
            for (int i = 0; i < 2; ++i)
                #pragma unroll
                for (int j = 0; j < 8; ++j)
                    acc[i][j] = MFMA16(af[i], bfr[j], acc[i][j]);
        }
    }

    // C layout: col = lane&15, row = 4*(lane>>4) + reg
    if constexpr (TRANS_OUT) {
        __bf16* Y = (__bf16*)Yv;
        #pragma unroll
        for (int i = 0; i < 2; ++i) {
            int mbase = row0 + wr * 32 + i * 16 + 4 * lg;
            int bb = mbase >> 12, mm = mbase & 4095;
            #pragma unroll
            for (int j = 0; j < 8; ++j) {
                int n = wc * 128 + j * 16 + lr;
                bf16x4v pk = { (__bf16)acc[i][j][0], (__bf16)acc[i][j][1],
                               (__bf16)acc[i][j][2], (__bf16)acc[i][j][3] };
                *(bf16x4v*)&Y[(((size_t)bb * 256 + n) << 12) + mm] = pk;
            }
        }
    } else if constexpr (OUT_F32) {
        float* Y = (float*)Yv;
        #pragma unroll
        for (int i = 0; i < 2; ++i)
            #pragma unroll
            for (int j = 0; j < 8; ++j) {
                int n = wc * 128 + j * 16 + lr;
                #pragma unroll
                for (int r = 0; r < 4; ++r) {
                    int m = row0 + wr * 32 + i * 16 + 4 * lg + r;
                    Y[(size_t)m * 256 + n] = acc[i][j][r];
                }
            }
    } else {
        __bf16* Y = (__bf16*)Yv;
        #pragma unroll
        for (int i = 0; i < 2; ++i)
            #pragma unroll
            for (int j = 0; j < 8; ++j) {
                int n = wc * 128 + j * 16 + lr;
                #pragma unroll
                for (int r = 0; r < 4; ++r) {
                    int m = row0 + wr * 32 + i * 16 + 4 * lg + r;
                    Y[(size_t)m * 256 + n] = (__bf16)(acc[i][j][r] * oscale);
                }
            }
    }
}

// ------- flash attention: swapped QK^T, 32x32 MFMA, KVBLK=64, 8 waves, dbuf gload_lds --
// grid 256: b=bid&7 (XCD pin), split=(bid>>3)&3 (1024 keys), qb=bid>>5 (256 q rows)
// 8 waves x 32 q. Partials: NORMALIZED O (bf16) per split + ml (m, l per q, f32).
__global__ __launch_bounds__(512, 1)
void attn_kernel(const __bf16* __restrict__ qh, const __bf16* __restrict__ kh,
                 const __bf16* __restrict__ vt, const int* __restrict__ mask,
                 __bf16* __restrict__ part, float* __restrict__ ml)
{
    extern __shared__ char smem[];   // [2][ K 64x512B | Vt 256x128B ] = 2 x 64KB

    const int t = threadIdx.x, lane = t & 63, w = t >> 6;   // 8 waves
    const int col = lane & 31, hi = lane >> 5;
    const int bid = blockIdx.x;
    const int b = bid & 7, rest = bid >> 3;
    const int split = rest & 3, qb = rest >> 2;
    const int q0 = qb * 256;
    const int kbase = split * 1024;

    // Q fragments (B-operand): lane holds Q[q0+w*32+col][d = s*16 + hi*8 + j]
    bf16x8 qf[16];
    {
        const size_t qrow = (size_t)b * 2048 + q0 + w * 32 + col;
        #pragma unroll
        for (int s = 0; s < 16; ++s)
            qf[s] = *(const bf16x8*)&qh[qrow * 256 + s * 16 + 8 * hi];
    }

    // per-lane gload source offsets (bytes); XOR involutions on both sides (rule #21)
    int koff[4];
    #pragma unroll
    for (int i = 0; i < 4; ++i) {
        int rrel = i * 2 + hi;                       // K row within wave, 0..7
        koff[i] = rrel * 512 + ((col ^ rrel) << 4);
    }
    // V: wave owns 32 d-rows (w*32..), 4 gl16 x 8 rows; src chunk = (l&7) ^ (rl&7)
    const int voffl = ((lane >> 3) << 13) + (((lane & 7) ^ ((lane >> 3) & 7)) << 4);

    const char* kp = (const char*)(kh + ((size_t)b * 4096 + kbase + w * 8) * 256);
    const char* vp = (const char*)(vt + ((size_t)(b * 256 + w * 32)) * 4096 + kbase);

    auto stage = [&](int kt, int buf) {
        const char* ks = kp + (size_t)kt * 32768;    // +64 keys * 512B
        const char* vs = vp + (size_t)kt * 128;      // +64 keys * 2B per d-row
        char* kd = smem + buf * 65536 + w * 4096;
        char* vd = smem + buf * 65536 + 32768 + w * 4096;
        #pragma unroll
        for (int i = 0; i < 4; ++i) gl16(ks + koff[i], kd + i * 1024 + lane * 16);
        #pragma unroll
        for (int i = 0; i < 4; ++i) gl16(vs + voffl + i * 65536, vd + i * 1024 + (lane & 63) * 16);
    };
    // NOTE: gl16 dest is wave-uniform base + lane*16; we pass the full per-lane address
    // minus lane*16 ambiguity by adding it explicitly (linear within each 1KB chunk).

    f32x16 o[8] = {};
    float m_run = -3.0e38f, lsum = 0.0f;
    const u32x4 onesf = { hi ? 0u : 0x00003F80u, 0u, 0u, 0u };  // bf16 1.0 at k=0

    int mv = mask[b * 4096 + kbase + lane];
    stage(0, 0);
    __syncthreads();
    int cur = 0;

    for (int kt = 0; kt < 16; ++kt) {
        int mvn = 0;
        if (kt + 1 < 16) {                            // prefetch next tile
            stage(kt + 1, cur ^ 1);
            mvn = mask[b * 4096 + kbase + (kt + 1) * 64 + lane];
        }
        const char* lk = smem + cur * 65536;
        const char* lv = smem + cur * 65536 + 32768;

        // rank-1 mask: st0 keys 0..31 (madd from lane=key), st1 keys 32..63
        float mh = mv ? 0.0f : MADD;
        float mo = __shfl_xor(mh, 32);
        u32x4 mf0 = { hi ? 0u : pk2(mh, 0.0f), 0u, 0u, 0u };
        u32x4 mf1 = { hi ? 0u : pk2(mo, 0.0f), 0u, 0u, 0u };
        f32x16 st0 = {}, st1 = {};
        st0 = MFMA32(__builtin_bit_cast(bf16x8, mf0), __builtin_bit_cast(bf16x8, onesf), st0);
        st1 = MFMA32(__builtin_bit_cast(bf16x8, mf1), __builtin_bit_cast(bf16x8, onesf), st1);

        // S^T = K Q^T : keys col (st0) and col+32 (st1); lane owns q=col
        __builtin_amdgcn_s_setprio(1);
        #pragma unroll
        for (int s = 0; s < 16; ++s) {
            int ch = ((2 * s + hi) ^ (col & 7)) << 4;
            bf16x8 ka0 = *(const bf16x8*)(lk + col * 512 + ch);
            bf16x8 ka1 = *(const bf16x8*)(lk + (col + 32) * 512 + ch);
            st0 = MFMA32(ka0, qf[s], st0);
            st1 = MFMA32(ka1, qf[s], st1);
        }
        __builtin_amdgcn_s_setprio(0);

        // online softmax over 64 keys, fully in-register
        float pmax = st0[0];
        #pragma unroll
        for (int r = 1; r < 16; ++r) pmax = fmaxf(pmax, st0[r]);
        #pragma unroll
        for (int r = 0; r < 16; ++r) pmax = fmaxf(pmax, st1[r]);
        pmax = fmaxf(pmax, __shfl_xor(pmax, 32));
        if (__any(pmax > m_run + 8.0f)) {             // defer-max (T13)
            float mnew = fmaxf(m_run, pmax);
            float alpha = exp2f(m_run - mnew);
            m_run = mnew;
            lsum *= alpha;
            #pragma unroll
            for (int r = 0; r < 16; ++r) {
                float a = __shfl(alpha, (r & 3) + 8 * (r >> 2) + 4 * hi);
                #pragma unroll
                for (int dt = 0; dt < 8; ++dt) o[dt][r] *= a;
            }
        }
        #pragma unroll
        for (int r = 0; r < 16; ++r) st0[r] = exp2f(st0[r] - m_run);
        #pragma unroll
        for (int r = 0; r < 16; ++r) st1[r] = exp2f(st1[r] - m_run);
        {   // tree-sum into lsum
            float s0 = 0, s1 = 0, s2 = 0, s3 = 0;
            #pragma unroll
            for (int r = 0; r < 4; ++r) {
                s0 += st0[r] + st0[r + 4]; s1 += st0[r + 8] + st0[r + 12];
                s2 += st1[r] + st1[r + 4]; s3 += st1[r + 8] + st1[r + 12];
            }
            lsum += (s0 + s1) + (s2 + s3);
        }

        // repack P (4 chunks of K=16) + PV: O[32q][256d] += P[32q][64k] V[64k][256d]
        __builtin_amdgcn_s_setprio(1);
        #pragma unroll
        for (int c = 0; c < 4; ++c) {
            const f32x16& pp = (c < 2) ? st0 : st1;
            int rb = (c & 1) * 8;
            u32 a0 = pk2(pp[rb + 0], pp[rb + 1]);
            u32 a1 = pk2(pp[rb + 2], pp[rb + 3]);
            u32 b0 = pk2(pp[rb + 4], pp[rb + 5]);
            u32 b1 = pk2(pp[rb + 6], pp[rb + 7]);
            u32 a0s = __shfl_xor((int)a0, 32), a1s = __shfl_xor((int)a1, 32);
            u32 b0s = __shfl_xor((int)b0, 32), b1s = __shfl_xor((int)b1, 32);
            u32x4 pa;
            pa[0] = hi ? b0s : a0;  pa[1] = hi ? b1s : a1;
            pa[2] = hi ? b0  : a0s; pa[3] = hi ? b1  : a1s;
            bf16x8 paf = __builtin_bit_cast(bf16x8, pa);
            #pragma unroll
            for (int dt = 0; dt < 8; ++dt) {
                bf16x8 vb = *(const bf16x8*)(lv + (dt * 32 + col) * 128 +
                                             ((((c << 1) | hi) ^ (col & 7)) << 4));
                o[dt] = MFMA32(paf, vb, o[dt]);
            }
        }
        __builtin_amdgcn_s_setprio(0);

        mv = mvn;
        __syncthreads();                              // drains vmcnt(0) + barrier
        cur ^= 1;
    }

    // epilogue: merge l across halves; store m/l + NORMALIZED bf16 O partial
    lsum += __shfl_xor(lsum, 32);
    if (lane < 32) {
        size_t qa = (size_t)b * 2048 + q0 + w * 32 + lane;
        ml[((size_t)split * 16384 + qa) * 2]     = m_run;
        ml[((size_t)split * 16384 + qa) * 2 + 1] = lsum;
    }
    float inv = 1.0f / lsum;
    #pragma unroll
    for (int r = 0; r < 16; ++r) {
        int ql = (r & 3) + 8 * (r >> 2) + 4 * hi;
        float ir = __shfl(inv, ql);
        size_t base = ((size_t)split * 16384 + (size_t)b * 2048 + q0 + w * 32 + ql) * 256;
        #pragma unroll
        for (int dt = 0; dt < 8; ++dt)
            part[base + dt * 32 + col] = (__bf16)(o[dt][r] * ir);
    }
}

// ---------------- combine KV-splits (bf16 normalized partials) ----------------
__global__ __launch_bounds__(256, 8)
void combine_kernel(const __bf16* __restrict__ part, const float* __restrict__ ml,
                    __bf16* __restrict__ xh)
{
    int tid = blockIdx.x * 256 + threadIdx.x;        // 16384 rows x 32 chunks of 8
    int row = tid >> 5, d8 = (tid & 31) * 8;
    float mm[4], ll[4];
    #pragma unroll
    for (int s = 0; s < 4; ++s) {
        mm[s] = ml[((size_t)s * 16384 + row) * 2];
        ll[s] = ml[((size_t)s * 16384 + row) * 2 + 1];
    }
    float ms = fmaxf(fmaxf(mm[0], mm[1]), fmaxf(mm[2], mm[3]));
    float ws[4], L = 0.0f;
    #pragma unroll
    for (int s = 0; s < 4; ++s) { ws[s] = ll[s] * exp2f(mm[s] - ms); L += ws[s]; }
    float acc[8] = {};
    #pragma unroll
    for (int s = 0; s < 4; ++s) {
        bf16x8 v = *(const bf16x8*)&part[((size_t)s * 16384 + row) * 256 + d8];
        #pragma unroll
        for (int j = 0; j < 8; ++j) acc[j] += ws[s] * (float)v[j];
    }
    float invL = 1.0f / L;
    bf16x8 o8;
    #pragma unroll
    for (int j = 0; j < 8; ++j) o8[j] = (__bf16)(acc[j] * invL);
    *(bf16x8*)&xh[(size_t)row * 256 + d8] = o8;
}

extern "C" void kernel_launch(void* const* d_in, const int* in_sizes, int n_in,
                              void* d_out, int out_size, void* d_ws, size_t ws_size,
                              hipStream_t stream)
{
    (void)in_sizes; (void)n_in; (void)out_size; (void)ws_size;
    const float* q  = (const float*)d_in[0];
    const float* k  = (const float*)d_in[1];
    const float* v  = (const float*)d_in[2];
    const int* mask = (const int*)d_in[3];
    const float* Wq = (const float*)d_in[4];
    const float* Wk = (const float*)d_in[5];
    const float* Wv = (const float*)d_in[6];
    const float* Wp = (const float*)d_in[7];
    float* out = (float*)d_out;

    __bf16* qh  = (__bf16*)d_ws;                   //  8.4 MB [16384][256]
    __bf16* kh  = qh + (size_t)16384 * 256;        // 16.8 MB [32768][256]
    __bf16* vt  = kh + (size_t)32768 * 256;        // 16.8 MB [8][256][4096]
    __bf16* wbf = vt + (size_t)32768 * 256;        //  0.5 MB [4][256][256] pre-swizzled

    // dead input buffers as scratch (stream-ordered reuse):
    __bf16* part = (__bf16*)d_in[1];               // [4][16384][256] bf16 = 33.5 MB
    float*  mlp  = (float*)d_in[0];                // [4][16384][2] f32
    __bf16* xh   = (__bf16*)d_in[2];               // [16384][256] bf16 (v dead after proj-v)

    wcvt_kernel<<<128, 256, 0, stream>>>(Wq, Wk, Wv, Wp, wbf);

    proj_kernel<true,  false, false><<<256, 256, 0, stream>>>(q, wbf,           qh, QSCALE);
    proj_kernel<true,  false, false><<<512, 256, 0, stream>>>(k, wbf + 65536,   kh, 1.0f);
    proj_kernel<true,  false, true ><<<512, 256, 0, stream>>>(v, wbf + 131072,  vt, 1.0f);

    hipFuncSetAttribute((const void*)attn_kernel,
                        hipFuncAttributeMaxDynamicSharedMemorySize, 131072);
    attn_kernel<<<256, 512, 131072, stream>>>(qh, kh, vt, mask, part, mlp);
    combine_kernel<<<2048, 256, 0, stream>>>(part, mlp, xh);

    proj_kernel<false, true,  false><<<256, 256, 0, stream>>>(xh, wbf + 196608, out, 1.0f);
}

// Round 6
// 282.537 us; speedup vs baseline: 1.6339x; 1.6339x over previous
//
#include <hip/hip_runtime.h>
#include <hip/hip_bf16.h>

typedef __bf16 bf16x8 __attribute__((ext_vector_type(8)));
typedef __bf16 bf16x4v __attribute__((ext_vector_type(4)));
typedef float f32x4 __attribute__((ext_vector_type(4)));
typedef float f32x16 __attribute__((ext_vector_type(16)));
typedef unsigned int u32;
typedef u32 u32x4 __attribute__((ext_vector_type(4)));
typedef unsigned short u16;

#define MFMA16(a, b, c) __builtin_amdgcn_mfma_f32_16x16x32_bf16((a), (b), (c), 0, 0, 0)
#define MFMA32(a, b, c) __builtin_amdgcn_mfma_f32_32x32x16_bf16((a), (b), (c), 0, 0, 0)

static constexpr float QSCALE = 0.09016844f;   // 256^-0.5 * log2(e) (folded into qh)
static constexpr float MADD   = -14427.0f;     // -10000 * log2(e)   (rank-1 mask add)

__device__ inline u32 pk2(float a, float b) {
    u16 x = __builtin_bit_cast(u16, (__bf16)a);
    u16 y = __builtin_bit_cast(u16, (__bf16)b);
    return (u32)x | ((u32)y << 16);
}

// async global->LDS, 16B per lane, linear dest (wave-uniform base + lane*16)
__device__ inline void gl16(const void* g, void* l) {
    __builtin_amdgcn_global_load_lds((const __attribute__((address_space(1))) u32*)g,
                                     (__attribute__((address_space(3))) u32*)l, 16, 0, 0);
}

// ------------- weight pre-convert: f32 [256][256] -> bf16, XOR-pre-swizzled -------------
// wbf[n][g] = W[n][ (g&~7) | ((g&7)^(n&7)) ]   (g = 16B chunk index, 0..31)
__global__ __launch_bounds__(256, 8)
void wcvt_kernel(const float* __restrict__ Wq, const float* __restrict__ Wk,
                 const float* __restrict__ Wv, const float* __restrict__ Wp,
                 __bf16* __restrict__ wbf)
{
    const int bid = blockIdx.x;            // 128 blocks: widx = bid>>5
    const int widx = bid >> 5;
    const float* W = widx == 0 ? Wq : widx == 1 ? Wk : widx == 2 ? Wv : Wp;
    const int tid = (bid & 31) * 256 + threadIdx.x;   // 0..8191
    const int n = tid >> 5, g = tid & 31;
    const int sg = (g & ~7) | ((g & 7) ^ (n & 7));
    const float* src = W + n * 256 + sg * 8;
    float4 a = *(const float4*)src;
    float4 b = *(const float4*)(src + 4);
    bf16x8 o8 = { (__bf16)a.x, (__bf16)a.y, (__bf16)a.z, (__bf16)a.w,
                  (__bf16)b.x, (__bf16)b.y, (__bf16)b.z, (__bf16)b.w };
    *(bf16x8*)&wbf[(size_t)widx * 65536 + n * 256 + g * 8] = o8;
}

// ---------------- projection GEMM: Y = X @ W^T, 64M x 256N block ----------------
// X: [M,256] (f32 or bf16); wbf: pre-swizzled bf16 W (row n = weights of out col n)
// Y bf16 (scaled) or f32; TRANS_OUT: per-4096-row batch, write Y^T [b][n][m%4096] bf16.
template<bool IN_F32, bool OUT_F32, bool TRANS_OUT>
__global__ __launch_bounds__(256, 2)
void proj_kernel(const void* __restrict__ Xv, const __bf16* __restrict__ wbf,
                 void* __restrict__ Yv, float oscale)
{
    __shared__ __bf16 lds_a[64][72];       // X tile, padded
    __shared__ __bf16 lds_w[256][64];      // W k-slice [256 n][64 k], XOR-swizzled chunks
    const int t = threadIdx.x;
    const int row0 = blockIdx.x * 64;
    const int lane = t & 63, w = t >> 6;
    const int wr = w >> 1, wc = w & 1;     // 2x2 waves: 32-row x 128-col
    const int lr = lane & 15, lg = lane >> 4;

    f32x4 acc[2][8] = {};

    for (int kk = 0; kk < 4; ++kk) {
        __syncthreads();
        // W stage: pure async copy (swizzle pre-baked in wbf)
        {
            char* lw = (char*)&lds_w[0][0];
            const char* src = (const char*)(wbf + kk * 64);   // row n stride 512B
            #pragma unroll
            for (int i = 0; i < 8; ++i) {
                int r = i * 32 + w * 8 + (lane >> 3);          // 0..255
                gl16(src + (size_t)r * 512 + (lane & 7) * 16,
                     lw + i * 4096 + w * 1024);
            }
        }
        if constexpr (IN_F32) {
            const float* X = (const float*)Xv;
            #pragma unroll
            for (int p = 0; p < 4; ++p) {
                int idx4 = p * 256 + t;                        // 1024 float4 (64x64)
                int r = idx4 >> 4, c4 = (idx4 & 15) << 2;
                float4 v4 = *(const float4*)&X[(size_t)(row0 + r) * 256 + kk * 64 + c4];
                bf16x4v pk = { (__bf16)v4.x, (__bf16)v4.y, (__bf16)v4.z, (__bf16)v4.w };
                *(bf16x4v*)&lds_a[r][c4] = pk;
            }
        } else {
            const __bf16* X = (const __bf16*)Xv;
            #pragma unroll
            for (int p = 0; p < 2; ++p) {
                int idx8 = p * 256 + t;                        // 512 chunks of 8 bf16
                int r = idx8 >> 3, c8 = (idx8 & 7) << 3;
                *(bf16x8*)&lds_a[r][c8] = *(const bf16x8*)&X[(size_t)(row0 + r) * 256 + kk * 64 + c8];
            }
        }
        __syncthreads();
        #pragma unroll
        for (int ks = 0; ks < 2; ++ks) {
            bf16x8 af[2], bfr[8];
            #pragma unroll
            for (int i = 0; i < 2; ++i)
                af[i] = *(bf16x8*)&lds_a[wr * 32 + i * 16 + lr][ks * 32 + 8 * lg];
            #pragma unroll
            for (int j = 0; j < 8; ++j) {
                int rw = wc * 128 + j * 16 + lr;
                int ch = (ks * 4 + lg) ^ (rw & 7);
                bfr[j] = *(bf16x8*)((char*)&lds_w[0][0] + rw * 128 + ch * 16);
            }
            #pragma unroll
            for (int i = 0; i < 2; ++i)
                #pragma unroll
                for (int j = 0; j < 8; ++j)
                    acc[i][j] = MFMA16(af[i], bfr[j], acc[i][j]);
        }
    }

    // C layout: col = lane&15, row = 4*(lane>>4) + reg
    if constexpr (TRANS_OUT) {
        __bf16* Y = (__bf16*)Yv;
        #pragma unroll
        for (int i = 0; i < 2; ++i) {
            int mbase = row0 + wr * 32 + i * 16 + 4 * lg;
            int bb = mbase >> 12, mm = mbase & 4095;
            #pragma unroll
            for (int j = 0; j < 8; ++j) {
                int n = wc * 128 + j * 16 + lr;
                bf16x4v pk = { (__bf16)acc[i][j][0], (__bf16)acc[i][j][1],
                               (__bf16)acc[i][j][2], (__bf16)acc[i][j][3] };
                *(bf16x4v*)&Y[(((size_t)bb * 256 + n) << 12) + mm] = pk;
            }
        }
    } else if constexpr (OUT_F32) {
        float* Y = (float*)Yv;
        #pragma unroll
        for (int i = 0; i < 2; ++i)
            #pragma unroll
            for (int j = 0; j < 8; ++j) {
                int n = wc * 128 + j * 16 + lr;
                #pragma unroll
                for (int r = 0; r < 4; ++r) {
                    int m = row0 + wr * 32 + i * 16 + 4 * lg + r;
                    Y[(size_t)m * 256 + n] = acc[i][j][r];
                }
            }
    } else {
        __bf16* Y = (__bf16*)Yv;
        #pragma unroll
        for (int i = 0; i < 2; ++i)
            #pragma unroll
            for (int j = 0; j < 8; ++j) {
                int n = wc * 128 + j * 16 + lr;
                #pragma unroll
                for (int r = 0; r < 4; ++r) {
                    int m = row0 + wr * 32 + i * 16 + 4 * lg + r;
                    Y[(size_t)m * 256 + n] = (__bf16)(acc[i][j][r] * oscale);
                }
            }
    }
}

// ---------------- flash attention: swapped QK^T, 32x32 MFMA, KVBLK=32, dbuf gload_lds --
// grid 512: b=bid&7 (XCD pin), split=(bid>>3)&3 (1024 keys), qb=bid>>5 (128 q rows)
// 4 waves x 32 q. Partials: NORMALIZED O (bf16) per split + ml (m, l per q, f32).
__global__ __launch_bounds__(256, 2)
void attn_kernel(const __bf16* __restrict__ qh, const __bf16* __restrict__ kh,
                 const __bf16* __restrict__ vt, const int* __restrict__ mask,
                 __bf16* __restrict__ part, float* __restrict__ ml)
{
    extern __shared__ char smem[];   // [2][ K 32x512B | Vt 256x64B ] = 2 x 32KB

    const int t = threadIdx.x, lane = t & 63, w = t >> 6;
    const int col = lane & 31, hi = lane >> 5;
    const int bid = blockIdx.x;
    const int b = bid & 7, rest = bid >> 3;
    const int split = rest & 3, qb = rest >> 2;
    const int q0 = qb * 128;
    const int kbase = split * 1024;

    // Q fragments (B-operand): lane holds Q[q0+w*32+col][d = s*16 + hi*8 + j]
    bf16x8 qf[16];
    {
        const size_t qrow = (size_t)b * 2048 + q0 + w * 32 + col;
        #pragma unroll
        for (int s = 0; s < 16; ++s)
            qf[s] = *(const bf16x8*)&qh[qrow * 256 + s * 16 + 8 * hi];
    }

    // per-lane gload source offsets (bytes); swizzles are XOR involutions (rule #21)
    // K rows: wave w owns rows w*8 + i*2 + hi; slot=col; src chunk = col ^ (rrel&7)
    int koff[4];
    #pragma unroll
    for (int i = 0; i < 4; ++i) {
        int rrel = i * 2 + hi;                       // 0..7
        koff[i] = rrel * 512 + ((col ^ rrel) << 4);
    }
    // V rows (d): wave w owns d = w*64 + i*16 + (lane>>2); slot=lane&3; src chunk = slot ^ ((d>>1)&3)
    const int voffl = ((lane >> 2) << 13) + (((lane & 3) ^ ((lane >> 3) & 3)) << 4);

    const char* kp = (const char*)(kh + ((size_t)b * 4096 + kbase + w * 8) * 256);
    const char* vp = (const char*)(vt + ((size_t)(b * 256 + w * 64)) * 4096 + kbase);

    auto stage = [&](int kt, int buf) {
        const char* ks = kp + (size_t)kt * 16384;    // +32 keys * 512B
        const char* vs = vp + (size_t)kt * 64;       // +32 keys * 2B per d-row
        char* kd = smem + buf * 32768 + w * 4096;
        char* vd = smem + buf * 32768 + 16384 + w * 4096;
        #pragma unroll
        for (int i = 0; i < 4; ++i) gl16(ks + koff[i], kd + i * 1024);
        #pragma unroll
        for (int i = 0; i < 4; ++i) gl16(vs + voffl + i * 131072, vd + i * 1024);
    };

    f32x16 o[8] = {};
    float m_run = -3.0e38f, lsum = 0.0f;
    const u32x4 onesf = { hi ? 0u : 0x00003F80u, 0u, 0u, 0u };  // bf16 1.0 at k=0

    int mv = mask[b * 4096 + kbase + col];
    stage(0, 0);
    __syncthreads();                                  // drains vmcnt before barrier
    int cur = 0;

    for (int kt = 0; kt < 32; ++kt) {
        int mvn = 0;
        if (kt + 1 < 32) {                            // prefetch next tile (uniform branch)
            stage(kt + 1, cur ^ 1);
            mvn = mask[b * 4096 + kbase + (kt + 1) * 32 + col];
        }
        const char* lk = smem + cur * 32768;
        const char* lv = smem + cur * 32768 + 16384;

        // S^T init via rank-1 mask MFMA: D[key][q] = madd[key]
        float mh = mv ? 0.0f : MADD;
        u32x4 mf = { hi ? 0u : pk2(mh, 0.0f), 0u, 0u, 0u };
        f32x16 st = {};
        st = MFMA32(__builtin_bit_cast(bf16x8, mf), __builtin_bit_cast(bf16x8, onesf), st);

        // S^T = K Q^T (32 keys x 32 q); lane owns q=col, regs = 16 key slots (per hi)
        __builtin_amdgcn_s_setprio(1);
        #pragma unroll
        for (int s = 0; s < 16; ++s) {
            bf16x8 ka = *(const bf16x8*)(lk + col * 512 + (((2 * s + hi) ^ (col & 7)) << 4));
            st = MFMA32(ka, qf[s], st);
        }
        __builtin_amdgcn_s_setprio(0);

        // online softmax, fully in-register
        float pmax = st[0];
        #pragma unroll
        for (int r = 1; r < 16; ++r) pmax = fmaxf(pmax, st[r]);
        pmax = fmaxf(pmax, __shfl_xor(pmax, 32));
        if (__any(pmax > m_run + 8.0f)) {             // defer-max (T13)
            float mnew = fmaxf(m_run, pmax);
            float alpha = exp2f(m_run - mnew);
            m_run = mnew;
            lsum *= alpha;
            #pragma unroll
            for (int r = 0; r < 16; ++r) {
                float a = __shfl(alpha, (r & 3) + 8 * (r >> 2) + 4 * hi);
                #pragma unroll
                for (int dt = 0; dt < 8; ++dt) o[dt][r] *= a;
            }
        }
        #pragma unroll
        for (int r = 0; r < 16; ++r) { st[r] = exp2f(st[r] - m_run); lsum += st[r]; }

        // P repack (one chunk at a time) + PV: O[32q][256d] += P[32q][32k] V[32k][256d]
        __builtin_amdgcn_s_setprio(1);
        #pragma unroll
        for (int c = 0; c < 2; ++c) {
            u32 a0 = pk2(st[8 * c + 0], st[8 * c + 1]);
            u32 a1 = pk2(st[8 * c + 2], st[8 * c + 3]);
            u32 b0 = pk2(st[8 * c + 4], st[8 * c + 5]);
            u32 b1 = pk2(st[8 * c + 6], st[8 * c + 7]);
            u32 a0s = __shfl_xor((int)a0, 32), a1s = __shfl_xor((int)a1, 32);
            u32 b0s = __shfl_xor((int)b0, 32), b1s = __shfl_xor((int)b1, 32);
            u32x4 pa;
            pa[0] = hi ? b0s : a0;  pa[1] = hi ? b1s : a1;
            pa[2] = hi ? b0  : a0s; pa[3] = hi ? b1  : a1s;
            bf16x8 paf = __builtin_bit_cast(bf16x8, pa);
            #pragma unroll
            for (int dt = 0; dt < 8; ++dt) {
                bf16x8 vb = *(const bf16x8*)(lv + (dt * 32 + col) * 64 +
                                             ((((c << 1) | hi) ^ ((col >> 1) & 3)) << 4));
                o[dt] = MFMA32(paf, vb, o[dt]);
            }
        }
        __builtin_amdgcn_s_setprio(0);

        mv = mvn;
        __syncthreads();                              // drains vmcnt(0) + barrier
        cur ^= 1;
    }

    // epilogue: merge l across halves; store m/l + NORMALIZED bf16 O partial
    lsum += __shfl_xor(lsum, 32);
    if (lane < 32) {
        size_t qa = (size_t)b * 2048 + q0 + w * 32 + lane;
        ml[((size_t)split * 16384 + qa) * 2]     = m_run;
        ml[((size_t)split * 16384 + qa) * 2 + 1] = lsum;
    }
    float inv = 1.0f / lsum;
    #pragma unroll
    for (int r = 0; r < 16; ++r) {
        int ql = (r & 3) + 8 * (r >> 2) + 4 * hi;
        float ir = __shfl(inv, ql);
        size_t base = ((size_t)split * 16384 + (size_t)b * 2048 + q0 + w * 32 + ql) * 256;
        #pragma unroll
        for (int dt = 0; dt < 8; ++dt)
            part[base + dt * 32 + col] = (__bf16)(o[dt][r] * ir);
    }
}

// ---------------- combine KV-splits (bf16 normalized partials) ----------------
__global__ __launch_bounds__(256, 8)
void combine_kernel(const __bf16* __restrict__ part, const float* __restrict__ ml,
                    __bf16* __restrict__ xh)
{
    int tid = blockIdx.x * 256 + threadIdx.x;        // 16384 rows x 32 chunks of 8
    int row = tid >> 5, d8 = (tid & 31) * 8;
    float mm[4], ll[4];
    #pragma unroll
    for (int s = 0; s < 4; ++s) {
        mm[s] = ml[((size_t)s * 16384 + row) * 2];
        ll[s] = ml[((size_t)s * 16384 + row) * 2 + 1];
    }
    float ms = fmaxf(fmaxf(mm[0], mm[1]), fmaxf(mm[2], mm[3]));
    float ws[4], L = 0.0f;
    #pragma unroll
    for (int s = 0; s < 4; ++s) { ws[s] = ll[s] * exp2f(mm[s] - ms); L += ws[s]; }
    float acc[8] = {};
    #pragma unroll
    for (int s = 0; s < 4; ++s) {
        bf16x8 v = *(const bf16x8*)&part[((size_t)s * 16384 + row) * 256 + d8];
        #pragma unroll
        for (int j = 0; j < 8; ++j) acc[j] += ws[s] * (float)v[j];
    }
    float invL = 1.0f / L;
    bf16x8 o8;
    #pragma unroll
    for (int j = 0; j < 8; ++j) o8[j] = (__bf16)(acc[j] * invL);
    *(bf16x8*)&xh[(size_t)row * 256 + d8] = o8;
}

extern "C" void kernel_launch(void* const* d_in, const int* in_sizes, int n_in,
                              void* d_out, int out_size, void* d_ws, size_t ws_size,
                              hipStream_t stream)
{
    (void)in_sizes; (void)n_in; (void)out_size; (void)ws_size;
    const float* q  = (const float*)d_in[0];
    const float* k  = (const float*)d_in[1];
    const float* v  = (const float*)d_in[2];
    const int* mask = (const int*)d_in[3];
    const float* Wq = (const float*)d_in[4];
    const float* Wk = (const float*)d_in[5];
    const float* Wv = (const float*)d_in[6];
    const float* Wp = (const float*)d_in[7];
    float* out = (float*)d_out;

    __bf16* qh  = (__bf16*)d_ws;                   //  8.4 MB [16384][256]
    __bf16* kh  = qh + (size_t)16384 * 256;        // 16.8 MB [32768][256]
    __bf16* vt  = kh + (size_t)32768 * 256;        // 16.8 MB [8][256][4096]
    __bf16* wbf = vt + (size_t)32768 * 256;        //  0.5 MB [4][256][256] pre-swizzled

    // dead input buffers as scratch (stream-ordered reuse):
    __bf16* part = (__bf16*)d_in[1];               // [4][16384][256] bf16 = 33.5 MB
    float*  mlp  = (float*)d_in[0];                // [4][16384][2] f32
    __bf16* xh   = (__bf16*)d_in[2];               // [16384][256] bf16 (v dead after proj-v)

    wcvt_kernel<<<128, 256, 0, stream>>>(Wq, Wk, Wv, Wp, wbf);

    proj_kernel<true,  false, false><<<256, 256, 0, stream>>>(q, wbf,           qh, QSCALE);
    proj_kernel<true,  false, false><<<512, 256, 0, stream>>>(k, wbf + 65536,   kh, 1.0f);
    proj_kernel<true,  false, true ><<<512, 256, 0, stream>>>(v, wbf + 131072,  vt, 1.0f);

    hipFuncSetAttribute((const void*)attn_kernel,
                        hipFuncAttributeMaxDynamicSharedMemorySize, 65536);
    attn_kernel<<<512, 256, 65536, stream>>>(qh, kh, vt, mask, part, mlp);
    combine_kernel<<<2048, 256, 0, stream>>>(part, mlp, xh);

    proj_kernel<false, true,  false><<<256, 256, 0, stream>>>(xh, wbf + 196608, out, 1.0f);
}